// Round 11
// baseline (319.659 us; speedup 1.0000x reference)
//
#include <hip/hip_runtime.h>

// ChebNet classifier: 3x ChebConv(K=6) + 2x sparse pool + linear head.
// R10 post-mortem: outsplit WRITE 49.6MB vs 19.2 logical + VGPR=64 -> the
//     compiler picked the 64-reg bucket and spilled xv[]+TxPtrs (6 ptrs by
//     value) to scratch; spill = the amplification (R7 signature again).
// R11: (a) contiguous Tx slots (txbase + k*TXS) -- producers write layer
//     input directly into slot 0, kills the 6-pointer struct; (b) inner
//     loop restructured: w0..w3 then per-node {load xv, FMA} -- one xv
//     live; (c) NT=4 for layer-1 (16 out/thread), NT=2 layer-2.

#define TPB 256
#define NB   318      // buckets = ceil(162500/512)
#define BCAP 8192     // per-bucket capacity
#define EPB  4096     // edges per block, phase A
#define TXS  800000LL // floats per Tx slot

static inline int gs(long long n) { return (int)((n + TPB - 1) / TPB); }

struct Desc5 {
    const int* rows[5];
    const int* cols[5];
    const float* vals[5];
    int eoff[6];
    int doff[5];
};

// ---------- phase A: bin edges by bucket with per-block chunk reservation ----------

__global__ void k_binA(Desc5 d, int* __restrict__ gbcnt, int2* __restrict__ binrec,
                       int Etot) {
    __shared__ int2 srec[EPB];
    __shared__ unsigned short sbuck[EPB];
    __shared__ int scnt[NB], sbase[NB], slcur[NB];
    int tid = threadIdx.x;
    int e0 = blockIdx.x * EPB;
    int ne = min(EPB, Etot - e0);
    for (int b = tid; b < NB; b += 256) scnt[b] = 0;
    __syncthreads();
    for (int i = tid; i < ne; i += 256) {
        int e = e0 + i;
        int s = 0;
        while (e >= d.eoff[s + 1]) ++s;
        int le = e - d.eoff[s];
        int grow = d.doff[s] + d.rows[s][le];
        int col = d.cols[s][le];
        int vb = (s >= 3) ? __float_as_int(d.vals[s][le]) : 0;
        int b = grow >> 9;
        srec[i] = make_int2(((grow & 511) << 17) | col, vb);
        sbuck[i] = (unsigned short)b;
        atomicAdd(&scnt[b], 1);
    }
    __syncthreads();
    for (int b = tid; b < NB; b += 256) {
        sbase[b] = scnt[b] > 0 ? atomicAdd(&gbcnt[b], scnt[b]) : 0;
        slcur[b] = 0;
    }
    __syncthreads();
    for (int i = tid; i < ne; i += 256) {
        int b = sbuck[i];
        int off = atomicAdd(&slcur[b], 1);
        binrec[(long long)b * BCAP + sbase[b] + off] = srec[i];
    }
}

// exclusive scan of gbcnt[NB] -> gbbase[NB] (1 block, 64 threads)
__global__ void k_bscan(const int* __restrict__ gbcnt, int* __restrict__ gbbase) {
    int lane = threadIdx.x;
    int carry = 0;
    for (int base = 0; base < NB; base += 64) {
        int i = base + lane;
        int v = (i < NB) ? gbcnt[i] : 0;
        int s = v;
#pragma unroll
        for (int off = 1; off < 64; off <<= 1) {
            int t = __shfl_up(s, off, 64);
            if (lane >= off) s += t;
        }
        if (i < NB) gbbase[i] = carry + s - v;
        carry += __shfl(s, 63, 64);
    }
}

// ---------- phase B common: LDS count + block scan over 512 rows ----------

__device__ inline void bucket_count_scan(const int2* __restrict__ br, int ne,
                                         int* cnt, int* lexcl, int* wsum) {
    int tid = threadIdx.x;
    cnt[2 * tid] = 0; cnt[2 * tid + 1] = 0;
    __syncthreads();
    for (int i = tid; i < ne; i += 256)
        atomicAdd(&cnt[br[i].x >> 17], 1);
    __syncthreads();
    int c0 = cnt[2 * tid], c1 = cnt[2 * tid + 1], p = c0 + c1;
    int lane = tid & 63, wid = tid >> 6;
    int s = p;
#pragma unroll
    for (int off = 1; off < 64; off <<= 1) {
        int t = __shfl_up(s, off, 64);
        if (lane >= off) s += t;
    }
    if (lane == 63) wsum[wid] = s;
    __syncthreads();
    int add = 0;
    for (int w = 0; w < wid; ++w) add += wsum[w];
    int ep = add + s - p;
    lexcl[2 * tid] = ep; lexcl[2 * tid + 1] = ep + c0;
    __syncthreads();
}

// B1: rowptr + dinv
__global__ void k_B1(const int* __restrict__ gbcnt, const int* __restrict__ gbbase,
                     const int2* __restrict__ binrec, int* __restrict__ rowptr,
                     float* __restrict__ dinv, int ntot, int ndinv, int Etot) {
    __shared__ int cnt[512], lexcl[512], wsum[4];
    int bucket = blockIdx.x, tid = threadIdx.x;
    int ne = gbcnt[bucket];
    const int2* br = binrec + (long long)bucket * BCAP;
    bucket_count_scan(br, ne, cnt, lexcl, wsum);
    int base = gbbase[bucket];
    int row0 = bucket << 9;
    int nrows = min(512, ntot - row0);
    for (int lr = tid; lr < nrows; lr += 256) {
        int grow = row0 + lr;
        rowptr[grow] = base + lexcl[lr];
        if (grow < ndinv) {
            int c = cnt[lr];
            dinv[grow] = c > 0 ? 1.0f / sqrtf((float)c) : 0.f;
        }
    }
    if (bucket == 0 && tid == 0) rowptr[ntot] = Etot;
}

// B2: place edges into final rec[] (writes confined to this bucket's region)
__global__ void k_B2(const int* __restrict__ gbcnt, const int* __restrict__ gbbase,
                     const int2* __restrict__ binrec, const float* __restrict__ dinv,
                     int2* __restrict__ rec) {
    __shared__ int cnt[512], lexcl[512], lcur[512], wsum[4];
    int bucket = blockIdx.x, tid = threadIdx.x;
    int ne = gbcnt[bucket];
    const int2* br = binrec + (long long)bucket * BCAP;
    bucket_count_scan(br, ne, cnt, lexcl, wsum);
    lcur[2 * tid] = 0; lcur[2 * tid + 1] = 0;
    __syncthreads();
    int base = gbbase[bucket];
    int row0 = bucket << 9;
    for (int i = tid; i < ne; i += 256) {
        int2 r = br[i];
        int lr = r.x >> 17, col = r.x & 0x1FFFF;
        int grow = row0 + lr;
        int pos = base + lexcl[lr] + atomicAdd(&lcur[lr], 1);
        float wv;
        if (grow < 100000)      wv = dinv[col];
        else if (grow < 125000) wv = dinv[100000 + col];
        else if (grow < 131250) wv = dinv[125000 + col];
        else                    wv = __int_as_float(r.y);
        rec[pos] = make_int2(col, __float_as_int(wv));
    }
}

// pos (N0 x 3) -> tx slot 0 (N0 x 4, w = 0)
__global__ void k_pad4(const float* __restrict__ pos, float4* __restrict__ dst, int n) {
    int i = blockIdx.x * blockDim.x + threadIdx.x;
    if (i < n) dst[i] = make_float4(pos[3 * i], pos[3 * i + 1], pos[3 * i + 2], 0.f);
}

// ---------- gather SpMV (Cheb prop) ----------

template <int C>
__global__ void k_sprop_t(const int* __restrict__ rowptr, const int2* __restrict__ rec,
                          const float* __restrict__ dinv, const float* __restrict__ src,
                          const float* __restrict__ prev, float* __restrict__ dst,
                          int n, int mode) {
    constexpr int C4 = C / 4;
    int idx = blockIdx.x * blockDim.x + threadIdx.x;
    if (idx >= n * C4) return;
    int r = idx / C4, c4 = (idx - r * C4) * 4;
    int s0 = rowptr[r], s1 = rowptr[r + 1];
    float4 acca = make_float4(0.f, 0.f, 0.f, 0.f);
    float4 accb = make_float4(0.f, 0.f, 0.f, 0.f);
    int j = s0;
    for (; j + 2 <= s1; j += 2) {
        int2 ra = rec[j], rb = rec[j + 1];
        float wa = __int_as_float(ra.y), wb = __int_as_float(rb.y);
        float4 sa = *(const float4*)(src + (long long)ra.x * C + c4);
        float4 sb = *(const float4*)(src + (long long)rb.x * C + c4);
        acca.x += wa * sa.x; acca.y += wa * sa.y; acca.z += wa * sa.z; acca.w += wa * sa.w;
        accb.x += wb * sb.x; accb.y += wb * sb.y; accb.z += wb * sb.z; accb.w += wb * sb.w;
    }
    if (j < s1) {
        int2 rr = rec[j];
        float w = __int_as_float(rr.y);
        float4 s = *(const float4*)(src + (long long)rr.x * C + c4);
        acca.x += w * s.x; acca.y += w * s.y; acca.z += w * s.z; acca.w += w * s.w;
    }
    acca.x += accb.x; acca.y += accb.y; acca.z += accb.z; acca.w += accb.w;
    float m = -dinv[r];
    long long o = (long long)r * C + c4;
    float4 out;
    if (mode) {
        float4 p = *(const float4*)(prev + o);
        out.x = 2.f * m * acca.x - p.x; out.y = 2.f * m * acca.y - p.y;
        out.z = 2.f * m * acca.z - p.z; out.w = 2.f * m * acca.w - p.w;
    } else {
        out.x = m * acca.x; out.y = m * acca.y; out.z = m * acca.z; out.w = m * acca.w;
    }
    *(float4*)(dst + o) = out;
}

// ---------- pool0: out[r] = sum_j val_j * relu(x[col_j]) ----------

template <int C>
__global__ void k_spool4_t(const int* __restrict__ rowptr, const int2* __restrict__ rec,
                           const float* __restrict__ x, float* __restrict__ out, int n) {
    constexpr int C4 = C / 4;
    int idx = blockIdx.x * blockDim.x + threadIdx.x;
    if (idx >= n * C4) return;
    int r = idx / C4, c4 = (idx - r * C4) * 4;
    int s0 = rowptr[r], s1 = rowptr[r + 1];
    float4 acca = make_float4(0.f, 0.f, 0.f, 0.f);
    float4 accb = make_float4(0.f, 0.f, 0.f, 0.f);
    int j = s0;
    for (; j + 2 <= s1; j += 2) {
        int2 ra = rec[j], rb = rec[j + 1];
        float va = __int_as_float(ra.y), vb = __int_as_float(rb.y);
        float4 sa = *(const float4*)(x + (long long)ra.x * C + c4);
        float4 sb = *(const float4*)(x + (long long)rb.x * C + c4);
        acca.x += va * fmaxf(sa.x, 0.f); acca.y += va * fmaxf(sa.y, 0.f);
        acca.z += va * fmaxf(sa.z, 0.f); acca.w += va * fmaxf(sa.w, 0.f);
        accb.x += vb * fmaxf(sb.x, 0.f); accb.y += vb * fmaxf(sb.y, 0.f);
        accb.z += vb * fmaxf(sb.z, 0.f); accb.w += vb * fmaxf(sb.w, 0.f);
    }
    if (j < s1) {
        int2 rr = rec[j];
        float v = __int_as_float(rr.y);
        float4 s = *(const float4*)(x + (long long)rr.x * C + c4);
        acca.x += v * fmaxf(s.x, 0.f); acca.y += v * fmaxf(s.y, 0.f);
        acca.z += v * fmaxf(s.z, 0.f); acca.w += v * fmaxf(s.w, 0.f);
    }
    acca.x += accb.x; acca.y += accb.y; acca.z += accb.z; acca.w += accb.w;
    *(float4*)(out + (long long)r * C + c4) = acca;
}

// ---------- pool1 fused with layer-1 partial reduce + bias + relu ----------

template <int C, int KSPLIT>
__global__ void k_pool_f(const int* __restrict__ rowptr, const int2* __restrict__ rec,
                         const float* __restrict__ part, const float* __restrict__ bias,
                         float* __restrict__ out, int n, int partStride) {
    constexpr int C4 = C / 4;
    int idx = blockIdx.x * blockDim.x + threadIdx.x;
    if (idx >= n * C4) return;
    int r = idx / C4, c4 = (idx - r * C4) * 4;
    int s0 = rowptr[r], s1 = rowptr[r + 1];
    float4 bb = *(const float4*)(bias + c4);
    float4 acc = make_float4(0.f, 0.f, 0.f, 0.f);
    for (int j = s0; j < s1; ++j) {
        int2 rr = rec[j];
        float v = __int_as_float(rr.y);
        float4 x = bb;
#pragma unroll
        for (int s = 0; s < KSPLIT; ++s) {
            float4 p = *(const float4*)(part + (long long)s * partStride + (long long)rr.x * C + c4);
            x.x += p.x; x.y += p.y; x.z += p.z; x.w += p.w;
        }
        acc.x += v * fmaxf(x.x, 0.f); acc.y += v * fmaxf(x.y, 0.f);
        acc.z += v * fmaxf(x.z, 0.f); acc.w += v * fmaxf(x.w, 0.f);
    }
    *(float4*)(out + (long long)r * C + c4) = acc;
}

// ---------- layer-0 direct out-GEMM (CIN=3 stride 4, COUT=32) ----------

__global__ void k_outgemm0(float* __restrict__ out, const float* __restrict__ txbase,
                           const float* __restrict__ W, const float* __restrict__ b,
                           int n) {
    int idx = blockIdx.x * blockDim.x + threadIdx.x;
    if (idx >= n * 8) return;
    int node = idx >> 3, co = (idx & 7) * 4;
    float4 acc = *(const float4*)(b + co);
#pragma unroll
    for (int k = 0; k < 6; ++k) {
        float4 xv = *(const float4*)(txbase + k * TXS + (long long)node * 4);
        const float* Wk = W + k * 96 + co;
        float4 w0 = *(const float4*)(Wk);
        float4 w1 = *(const float4*)(Wk + 32);
        float4 w2 = *(const float4*)(Wk + 64);
        acc.x += xv.x * w0.x + xv.y * w1.x + xv.z * w2.x;
        acc.y += xv.x * w0.y + xv.y * w1.y + xv.z * w2.y;
        acc.z += xv.x * w0.z + xv.y * w1.z + xv.z * w2.z;
        acc.w += xv.x * w0.w + xv.y * w1.w + xv.z * w2.w;
    }
    *(float4*)(out + (long long)node * 32 + co) = acc;
}

// ---------- node-tiled k-split out-GEMM, low-pressure inner loop ----------
// Per c4-chunk: load w0..w3, then per node {load xv, FMA} (one xv live).
// Live regs ~ acc[NT](4*NT) + w(16) + xv(4). Requires n % NT == 0.

template <int CIN, int COUT, int KSPLIT, int NT>
__global__ __launch_bounds__(256, 4)
void k_outsplit4(float* __restrict__ part, const float* __restrict__ txbase,
                 const float* __restrict__ W, int n, int partStride) {
    constexpr int CO4 = COUT / 4;
    constexpr int KPER = 6 / KSPLIT;
    int per = (n / NT) * CO4;
    int idx = blockIdx.x * blockDim.x + threadIdx.x;
    if (idx >= per * KSPLIT) return;
    int s = idx / per, t = idx - s * per;
    int tile = t / CO4, co = (t - tile * CO4) * 4;
    int node0 = tile * NT;
    float4 acc[NT];
#pragma unroll
    for (int i = 0; i < NT; ++i) acc[i] = make_float4(0.f, 0.f, 0.f, 0.f);
#pragma unroll
    for (int kk = 0; kk < KPER; ++kk) {
        int k = s * KPER + kk;
        const float* xb = txbase + (long long)k * TXS + (long long)node0 * CIN;
        const float* Wk = W + (long long)k * CIN * COUT + co;
#pragma unroll
        for (int c4 = 0; c4 < CIN / 4; ++c4) {
            const float* Wr = Wk + c4 * 4 * COUT;
            float4 w0 = *(const float4*)(Wr);
            float4 w1 = *(const float4*)(Wr + COUT);
            float4 w2 = *(const float4*)(Wr + 2 * COUT);
            float4 w3 = *(const float4*)(Wr + 3 * COUT);
#pragma unroll
            for (int i = 0; i < NT; ++i) {
                float4 xv = *(const float4*)(xb + i * CIN + c4 * 4);
                acc[i].x += xv.x * w0.x + xv.y * w1.x + xv.z * w2.x + xv.w * w3.x;
                acc[i].y += xv.x * w0.y + xv.y * w1.y + xv.z * w2.y + xv.w * w3.y;
                acc[i].z += xv.x * w0.z + xv.y * w1.z + xv.z * w2.z + xv.w * w3.z;
                acc[i].w += xv.x * w0.w + xv.y * w1.w + xv.z * w2.w + xv.w * w3.w;
            }
        }
    }
    float* op = part + (long long)s * partStride + (long long)node0 * COUT + co;
#pragma unroll
    for (int i = 0; i < NT; ++i)
        *(float4*)(op + (long long)i * COUT) = acc[i];
}

// ---------- linear head, fused with layer-2 partial reduce + bias ----------

__global__ void k_linear_partial_f(const float* __restrict__ lw,
                                   const float4* __restrict__ part,
                                   const float* __restrict__ b2,
                                   float* __restrict__ partials,
                                   int len4, int len, int nblk) {
    float acc[10];
#pragma unroll
    for (int j = 0; j < 10; ++j) acc[j] = 0.f;
    const float4* b2v = (const float4*)b2;
    for (int i = blockIdx.x * blockDim.x + threadIdx.x; i < len4;
         i += gridDim.x * blockDim.x) {
        float4 xv = b2v[i & 31];
#pragma unroll
        for (int s = 0; s < 6; ++s) {
            float4 p = part[s * 200000 + i];
            xv.x += p.x; xv.y += p.y; xv.z += p.z; xv.w += p.w;
        }
#pragma unroll
        for (int j = 0; j < 10; ++j) {
            float4 wv = *(const float4*)(lw + (long long)j * len + i * 4);
            acc[j] += xv.x * wv.x + xv.y * wv.y + xv.z * wv.z + xv.w * wv.w;
        }
    }
    __shared__ float lds[4][10];
    int wid = threadIdx.x >> 6, lane = threadIdx.x & 63;
#pragma unroll
    for (int j = 0; j < 10; ++j) {
        float v = acc[j];
        for (int off = 32; off > 0; off >>= 1) v += __shfl_down(v, off, 64);
        if (lane == 0) lds[wid][j] = v;
    }
    __syncthreads();
    if (threadIdx.x < 10) {
        float s = lds[0][threadIdx.x] + lds[1][threadIdx.x] +
                  lds[2][threadIdx.x] + lds[3][threadIdx.x];
        partials[threadIdx.x * nblk + blockIdx.x] = s;
    }
}

__global__ void k_linear_final(const float* __restrict__ partials,
                               const float* __restrict__ lb,
                               float* __restrict__ out, int nblk) {
    int j = threadIdx.x >> 6, lane = threadIdx.x & 63;
    float v = 0.f;
    for (int b = lane; b < nblk; b += 64) v += partials[j * nblk + b];
    for (int off = 32; off > 0; off >>= 1) v += __shfl_down(v, off, 64);
    if (lane == 0) out[j] = lb[j] + v;
}

extern "C" void kernel_launch(void* const* d_in, const int* in_sizes, int n_in,
                              void* d_out, int out_size, void* d_ws, size_t ws_size,
                              hipStream_t stream) {
    const int cN0 = 100000, cN1 = 25000, cN2 = 6250;
    const int cE0 = 600000, cE1 = 150000, cE2 = 40000;
    const int NBLK = 512;

    const float* pos = (const float*)d_in[0];
    const int*   ei0 = (const int*)d_in[1];
    const int*   ei1 = (const int*)d_in[2];
    const int*   ei2 = (const int*)d_in[3];
    const int*   d0r = (const int*)d_in[4];
    const int*   d0c = (const int*)d_in[5];
    const float* d0v = (const float*)d_in[6];
    const int*   d1r = (const int*)d_in[7];
    const int*   d1c = (const int*)d_in[8];
    const float* d1v = (const float*)d_in[9];
    const float* W0  = (const float*)d_in[10];
    const float* b0  = (const float*)d_in[11];
    const float* W1  = (const float*)d_in[12];
    const float* b1  = (const float*)d_in[13];
    const float* W2  = (const float*)d_in[14];
    const float* b2  = (const float*)d_in[15];
    const float* lw  = (const float*)d_in[16];
    const float* lb  = (const float*)d_in[17];
    float* outZ = (float*)d_out;

    // concatenated row space: g0 g1 g2 p0 p1
    const int ntot = cN0 + cN1 + cN2 + cN1 + cN2;          // 162500
    const int Etot = cE0 + cE1 + cE2 + cN0 + cN1;          // 915000
    const int Eg   = cE0 + cE1 + cE2;                      // 790000
    const int ndinv = cN0 + cN1 + cN2;                     // 131250
    const int doff0 = 0, doff1 = cN0, doff2 = cN0 + cN1,
              doffp0 = doff2 + cN2, doffp1 = doffp0 + cN1;

    // workspace layout (4B units); int2/float4 bases 8/16B-aligned
    int*   iws    = (int*)d_ws;
    int*   gbcnt  = iws;                          // 320
    int*   gbbase = gbcnt + 320;                  // 320
    int*   rowptr = gbbase + 320;                 // 162504
    float* dinv   = (float*)(rowptr + 162504);    // 131256
    int2*  binrec = (int2*)(dinv + 131256);       // NB*BCAP int2
    int2*  rec    = binrec + (long long)NB * BCAP;// 915000 int2
    float* txbuf  = (float*)(rec + 915000);       // 6 x TXS (slot 0 = x)
    float* part   = txbuf + 6 * TXS;              // 4800000
    float* bufOut = part + 4800000;               // 3200000
    float* lpart  = bufOut + 3200000;             // 5120

    Desc5 d;
    d.rows[0] = ei0;        d.cols[0] = ei0 + cE0; d.vals[0] = nullptr;
    d.rows[1] = ei1;        d.cols[1] = ei1 + cE1; d.vals[1] = nullptr;
    d.rows[2] = ei2;        d.cols[2] = ei2 + cE2; d.vals[2] = nullptr;
    d.rows[3] = d0r;        d.cols[3] = d0c;       d.vals[3] = d0v;
    d.rows[4] = d1r;        d.cols[4] = d1c;       d.vals[4] = d1v;
    d.eoff[0] = 0;
    d.eoff[1] = cE0;
    d.eoff[2] = cE0 + cE1;
    d.eoff[3] = Eg;
    d.eoff[4] = Eg + cN0;
    d.eoff[5] = Etot;
    d.doff[0] = doff0; d.doff[1] = doff1; d.doff[2] = doff2;
    d.doff[3] = doffp0; d.doff[4] = doffp1;

    // ---- prep: pos -> tx slot 0 (stride 4) ----
    k_pad4<<<gs(cN0), TPB, 0, stream>>>(pos, (float4*)txbuf, cN0);

    // ---- binned CSR build ----
    hipMemsetAsync(gbcnt, 0, (size_t)NB * 4, stream);
    k_binA<<<(Etot + EPB - 1) / EPB, TPB, 0, stream>>>(d, gbcnt, binrec, Etot);
    k_bscan<<<1, 64, 0, stream>>>(gbcnt, gbbase);
    k_B1<<<NB, TPB, 0, stream>>>(gbcnt, gbbase, binrec, rowptr, dinv, ntot, ndinv, Etot);
    k_B2<<<NB, TPB, 0, stream>>>(gbcnt, gbbase, binrec, dinv, rec);

    // ---- Tx recurrence over contiguous slots (slot 0 = x) ----
    auto run_sprops = [&](int doffs, int n, int Cs) {
        const int* rp = rowptr + doffs;
        const float* dv = dinv + doffs;
        auto sprop = [&](int kdst, int mode) {
            const float* src = txbuf + (long long)(kdst - 1) * TXS;
            const float* prev = (kdst >= 2) ? txbuf + (long long)(kdst - 2) * TXS : nullptr;
            float* dst = txbuf + (long long)kdst * TXS;
            long long work = (long long)n * (Cs >> 2);
            if (Cs == 4)
                k_sprop_t<4><<<gs(work), TPB, 0, stream>>>(rp, rec, dv, src, prev, dst, n, mode);
            else if (Cs == 32)
                k_sprop_t<32><<<gs(work), TPB, 0, stream>>>(rp, rec, dv, src, prev, dst, n, mode);
            else
                k_sprop_t<64><<<gs(work), TPB, 0, stream>>>(rp, rec, dv, src, prev, dst, n, mode);
        };
        sprop(1, 0);
        for (int k = 2; k < 6; ++k) sprop(k, 1);
    };

    // ---- layer 0: tx0 = pos4 (CIN=3 s4) -> bufOut (N0x32); pool0 -> tx slot 0 ----
    run_sprops(doff0, cN0, 4);
    k_outgemm0<<<gs((long long)cN0 * 8), TPB, 0, stream>>>(bufOut, txbuf, W0, b0, cN0);
    k_spool4_t<32><<<gs((long long)cN1 * 8), TPB, 0, stream>>>(
        rowptr + doffp0, rec, bufOut, txbuf, cN1);

    // ---- layer 1: tx (N1x32) -> part[0..2]; pool1 fused -> tx slot 0 ----
    run_sprops(doff1, cN1, 32);
    {
        const int pstride = cN1 * 64;  // 1600000
        k_outsplit4<32, 64, 3, 4><<<gs((long long)(cN1 / 4) * 16 * 3), TPB, 0, stream>>>(
            part, txbuf, W1, cN1, pstride);
        k_pool_f<64, 3><<<gs((long long)cN2 * 16), TPB, 0, stream>>>(
            rowptr + doffp1, rec, part, b1, txbuf, cN2, pstride);
    }

    // ---- layer 2: tx (N2x64) -> part[0..5]; head fused ----
    run_sprops(doff2, cN2, 64);
    {
        const int pstride = cN2 * 128;  // 800000
        k_outsplit4<64, 128, 6, 2><<<gs((long long)(cN2 / 2) * 32 * 6), TPB, 0, stream>>>(
            part, txbuf, W2, cN2, pstride);
        k_linear_partial_f<<<NBLK, TPB, 0, stream>>>(
            lw, (const float4*)part, b2, lpart, cN2 * 128 / 4, cN2 * 128, NBLK);
        k_linear_final<<<1, 640, 0, stream>>>(lpart, lb, outZ, NBLK);
    }
}

// Round 12
// 263.488 us; speedup vs baseline: 1.2132x; 1.2132x over previous
//
#include <hip/hip_runtime.h>

// ChebNet classifier: 3x ChebConv(K=6) + 2x sparse pool + linear head.
// R11 post-mortem: outsplit spilled AGAIN (FETCH 82/WRITE 155MB vs 19+19
//     logical). Root cause: full unroll of the chunk loop = straight-line
//     body with 64-128 independent loads; scheduler hoists them all ->
//     200+ live regs -> scratch. Source order irrelevant.
// R12: #pragma unroll 1 on the chunk loops (live set = one iteration,
//     TLP hides latency -- 1172/2344 blocks). 4-chain unrolled k_sprop_c4
//     for the low-parallelism layer-0 gathers (100K threads, dep chains).

#define TPB 256
#define NB   318      // buckets = ceil(162500/512)
#define BCAP 8192     // per-bucket capacity
#define EPB  4096     // edges per block, phase A
#define TXS  800000LL // floats per Tx slot

static inline int gs(long long n) { return (int)((n + TPB - 1) / TPB); }

struct Desc5 {
    const int* rows[5];
    const int* cols[5];
    const float* vals[5];
    int eoff[6];
    int doff[5];
};

// ---------- phase A: bin edges by bucket with per-block chunk reservation ----------

__global__ void k_binA(Desc5 d, int* __restrict__ gbcnt, int2* __restrict__ binrec,
                       int Etot) {
    __shared__ int2 srec[EPB];
    __shared__ unsigned short sbuck[EPB];
    __shared__ int scnt[NB], sbase[NB], slcur[NB];
    int tid = threadIdx.x;
    int e0 = blockIdx.x * EPB;
    int ne = min(EPB, Etot - e0);
    for (int b = tid; b < NB; b += 256) scnt[b] = 0;
    __syncthreads();
    for (int i = tid; i < ne; i += 256) {
        int e = e0 + i;
        int s = 0;
        while (e >= d.eoff[s + 1]) ++s;
        int le = e - d.eoff[s];
        int grow = d.doff[s] + d.rows[s][le];
        int col = d.cols[s][le];
        int vb = (s >= 3) ? __float_as_int(d.vals[s][le]) : 0;
        int b = grow >> 9;
        srec[i] = make_int2(((grow & 511) << 17) | col, vb);
        sbuck[i] = (unsigned short)b;
        atomicAdd(&scnt[b], 1);
    }
    __syncthreads();
    for (int b = tid; b < NB; b += 256) {
        sbase[b] = scnt[b] > 0 ? atomicAdd(&gbcnt[b], scnt[b]) : 0;
        slcur[b] = 0;
    }
    __syncthreads();
    for (int i = tid; i < ne; i += 256) {
        int b = sbuck[i];
        int off = atomicAdd(&slcur[b], 1);
        binrec[(long long)b * BCAP + sbase[b] + off] = srec[i];
    }
}

// exclusive scan of gbcnt[NB] -> gbbase[NB] (1 block, 64 threads)
__global__ void k_bscan(const int* __restrict__ gbcnt, int* __restrict__ gbbase) {
    int lane = threadIdx.x;
    int carry = 0;
    for (int base = 0; base < NB; base += 64) {
        int i = base + lane;
        int v = (i < NB) ? gbcnt[i] : 0;
        int s = v;
#pragma unroll
        for (int off = 1; off < 64; off <<= 1) {
            int t = __shfl_up(s, off, 64);
            if (lane >= off) s += t;
        }
        if (i < NB) gbbase[i] = carry + s - v;
        carry += __shfl(s, 63, 64);
    }
}

// ---------- phase B common: LDS count + block scan over 512 rows ----------

__device__ inline void bucket_count_scan(const int2* __restrict__ br, int ne,
                                         int* cnt, int* lexcl, int* wsum) {
    int tid = threadIdx.x;
    cnt[2 * tid] = 0; cnt[2 * tid + 1] = 0;
    __syncthreads();
    for (int i = tid; i < ne; i += 256)
        atomicAdd(&cnt[br[i].x >> 17], 1);
    __syncthreads();
    int c0 = cnt[2 * tid], c1 = cnt[2 * tid + 1], p = c0 + c1;
    int lane = tid & 63, wid = tid >> 6;
    int s = p;
#pragma unroll
    for (int off = 1; off < 64; off <<= 1) {
        int t = __shfl_up(s, off, 64);
        if (lane >= off) s += t;
    }
    if (lane == 63) wsum[wid] = s;
    __syncthreads();
    int add = 0;
    for (int w = 0; w < wid; ++w) add += wsum[w];
    int ep = add + s - p;
    lexcl[2 * tid] = ep; lexcl[2 * tid + 1] = ep + c0;
    __syncthreads();
}

// B1: rowptr + dinv
__global__ void k_B1(const int* __restrict__ gbcnt, const int* __restrict__ gbbase,
                     const int2* __restrict__ binrec, int* __restrict__ rowptr,
                     float* __restrict__ dinv, int ntot, int ndinv, int Etot) {
    __shared__ int cnt[512], lexcl[512], wsum[4];
    int bucket = blockIdx.x, tid = threadIdx.x;
    int ne = gbcnt[bucket];
    const int2* br = binrec + (long long)bucket * BCAP;
    bucket_count_scan(br, ne, cnt, lexcl, wsum);
    int base = gbbase[bucket];
    int row0 = bucket << 9;
    int nrows = min(512, ntot - row0);
    for (int lr = tid; lr < nrows; lr += 256) {
        int grow = row0 + lr;
        rowptr[grow] = base + lexcl[lr];
        if (grow < ndinv) {
            int c = cnt[lr];
            dinv[grow] = c > 0 ? 1.0f / sqrtf((float)c) : 0.f;
        }
    }
    if (bucket == 0 && tid == 0) rowptr[ntot] = Etot;
}

// B2: place edges into final rec[] (writes confined to this bucket's region)
__global__ void k_B2(const int* __restrict__ gbcnt, const int* __restrict__ gbbase,
                     const int2* __restrict__ binrec, const float* __restrict__ dinv,
                     int2* __restrict__ rec) {
    __shared__ int cnt[512], lexcl[512], lcur[512], wsum[4];
    int bucket = blockIdx.x, tid = threadIdx.x;
    int ne = gbcnt[bucket];
    const int2* br = binrec + (long long)bucket * BCAP;
    bucket_count_scan(br, ne, cnt, lexcl, wsum);
    lcur[2 * tid] = 0; lcur[2 * tid + 1] = 0;
    __syncthreads();
    int base = gbbase[bucket];
    int row0 = bucket << 9;
    for (int i = tid; i < ne; i += 256) {
        int2 r = br[i];
        int lr = r.x >> 17, col = r.x & 0x1FFFF;
        int grow = row0 + lr;
        int pos = base + lexcl[lr] + atomicAdd(&lcur[lr], 1);
        float wv;
        if (grow < 100000)      wv = dinv[col];
        else if (grow < 125000) wv = dinv[100000 + col];
        else if (grow < 131250) wv = dinv[125000 + col];
        else                    wv = __int_as_float(r.y);
        rec[pos] = make_int2(col, __float_as_int(wv));
    }
}

// pos (N0 x 3) -> tx slot 0 (N0 x 4, w = 0)
__global__ void k_pad4(const float* __restrict__ pos, float4* __restrict__ dst, int n) {
    int i = blockIdx.x * blockDim.x + threadIdx.x;
    if (i < n) dst[i] = make_float4(pos[3 * i], pos[3 * i + 1], pos[3 * i + 2], 0.f);
}

// ---------- gather SpMV (Cheb prop) ----------

// C == 4 (layer 0): 4 independent accumulator chains for MLP at low TLP
__global__ void k_sprop_c4(const int* __restrict__ rowptr, const int2* __restrict__ rec,
                           const float* __restrict__ dinv, const float* __restrict__ src,
                           const float* __restrict__ prev, float* __restrict__ dst,
                           int n, int mode) {
    int r = blockIdx.x * blockDim.x + threadIdx.x;
    if (r >= n) return;
    int s0 = rowptr[r], s1 = rowptr[r + 1];
    float4 a0 = make_float4(0.f, 0.f, 0.f, 0.f);
    float4 a1 = a0, a2 = a0, a3 = a0;
    int j = s0;
    for (; j + 4 <= s1; j += 4) {
        int2 r0 = rec[j], r1 = rec[j + 1], r2 = rec[j + 2], r3 = rec[j + 3];
        float w0 = __int_as_float(r0.y), w1 = __int_as_float(r1.y);
        float w2 = __int_as_float(r2.y), w3 = __int_as_float(r3.y);
        float4 s0v = *(const float4*)(src + (long long)r0.x * 4);
        float4 s1v = *(const float4*)(src + (long long)r1.x * 4);
        float4 s2v = *(const float4*)(src + (long long)r2.x * 4);
        float4 s3v = *(const float4*)(src + (long long)r3.x * 4);
        a0.x += w0 * s0v.x; a0.y += w0 * s0v.y; a0.z += w0 * s0v.z; a0.w += w0 * s0v.w;
        a1.x += w1 * s1v.x; a1.y += w1 * s1v.y; a1.z += w1 * s1v.z; a1.w += w1 * s1v.w;
        a2.x += w2 * s2v.x; a2.y += w2 * s2v.y; a2.z += w2 * s2v.z; a2.w += w2 * s2v.w;
        a3.x += w3 * s3v.x; a3.y += w3 * s3v.y; a3.z += w3 * s3v.z; a3.w += w3 * s3v.w;
    }
    for (; j < s1; ++j) {
        int2 rr = rec[j];
        float w = __int_as_float(rr.y);
        float4 s = *(const float4*)(src + (long long)rr.x * 4);
        a0.x += w * s.x; a0.y += w * s.y; a0.z += w * s.z; a0.w += w * s.w;
    }
    a0.x += a1.x + a2.x + a3.x; a0.y += a1.y + a2.y + a3.y;
    a0.z += a1.z + a2.z + a3.z; a0.w += a1.w + a2.w + a3.w;
    float m = -dinv[r];
    long long o = (long long)r * 4;
    float4 out;
    if (mode) {
        float4 p = *(const float4*)(prev + o);
        out.x = 2.f * m * a0.x - p.x; out.y = 2.f * m * a0.y - p.y;
        out.z = 2.f * m * a0.z - p.z; out.w = 2.f * m * a0.w - p.w;
    } else {
        out.x = m * a0.x; out.y = m * a0.y; out.z = m * a0.z; out.w = m * a0.w;
    }
    *(float4*)(dst + o) = out;
}

template <int C>
__global__ void k_sprop_t(const int* __restrict__ rowptr, const int2* __restrict__ rec,
                          const float* __restrict__ dinv, const float* __restrict__ src,
                          const float* __restrict__ prev, float* __restrict__ dst,
                          int n, int mode) {
    constexpr int C4 = C / 4;
    int idx = blockIdx.x * blockDim.x + threadIdx.x;
    if (idx >= n * C4) return;
    int r = idx / C4, c4 = (idx - r * C4) * 4;
    int s0 = rowptr[r], s1 = rowptr[r + 1];
    float4 acca = make_float4(0.f, 0.f, 0.f, 0.f);
    float4 accb = make_float4(0.f, 0.f, 0.f, 0.f);
    int j = s0;
    for (; j + 2 <= s1; j += 2) {
        int2 ra = rec[j], rb = rec[j + 1];
        float wa = __int_as_float(ra.y), wb = __int_as_float(rb.y);
        float4 sa = *(const float4*)(src + (long long)ra.x * C + c4);
        float4 sb = *(const float4*)(src + (long long)rb.x * C + c4);
        acca.x += wa * sa.x; acca.y += wa * sa.y; acca.z += wa * sa.z; acca.w += wa * sa.w;
        accb.x += wb * sb.x; accb.y += wb * sb.y; accb.z += wb * sb.z; accb.w += wb * sb.w;
    }
    if (j < s1) {
        int2 rr = rec[j];
        float w = __int_as_float(rr.y);
        float4 s = *(const float4*)(src + (long long)rr.x * C + c4);
        acca.x += w * s.x; acca.y += w * s.y; acca.z += w * s.z; acca.w += w * s.w;
    }
    acca.x += accb.x; acca.y += accb.y; acca.z += accb.z; acca.w += accb.w;
    float m = -dinv[r];
    long long o = (long long)r * C + c4;
    float4 out;
    if (mode) {
        float4 p = *(const float4*)(prev + o);
        out.x = 2.f * m * acca.x - p.x; out.y = 2.f * m * acca.y - p.y;
        out.z = 2.f * m * acca.z - p.z; out.w = 2.f * m * acca.w - p.w;
    } else {
        out.x = m * acca.x; out.y = m * acca.y; out.z = m * acca.z; out.w = m * acca.w;
    }
    *(float4*)(dst + o) = out;
}

// ---------- pool0: out[r] = sum_j val_j * relu(x[col_j]) ----------

template <int C>
__global__ void k_spool4_t(const int* __restrict__ rowptr, const int2* __restrict__ rec,
                           const float* __restrict__ x, float* __restrict__ out, int n) {
    constexpr int C4 = C / 4;
    int idx = blockIdx.x * blockDim.x + threadIdx.x;
    if (idx >= n * C4) return;
    int r = idx / C4, c4 = (idx - r * C4) * 4;
    int s0 = rowptr[r], s1 = rowptr[r + 1];
    float4 acca = make_float4(0.f, 0.f, 0.f, 0.f);
    float4 accb = make_float4(0.f, 0.f, 0.f, 0.f);
    int j = s0;
    for (; j + 2 <= s1; j += 2) {
        int2 ra = rec[j], rb = rec[j + 1];
        float va = __int_as_float(ra.y), vb = __int_as_float(rb.y);
        float4 sa = *(const float4*)(x + (long long)ra.x * C + c4);
        float4 sb = *(const float4*)(x + (long long)rb.x * C + c4);
        acca.x += va * fmaxf(sa.x, 0.f); acca.y += va * fmaxf(sa.y, 0.f);
        acca.z += va * fmaxf(sa.z, 0.f); acca.w += va * fmaxf(sa.w, 0.f);
        accb.x += vb * fmaxf(sb.x, 0.f); accb.y += vb * fmaxf(sb.y, 0.f);
        accb.z += vb * fmaxf(sb.z, 0.f); accb.w += vb * fmaxf(sb.w, 0.f);
    }
    if (j < s1) {
        int2 rr = rec[j];
        float v = __int_as_float(rr.y);
        float4 s = *(const float4*)(x + (long long)rr.x * C + c4);
        acca.x += v * fmaxf(s.x, 0.f); acca.y += v * fmaxf(s.y, 0.f);
        acca.z += v * fmaxf(s.z, 0.f); acca.w += v * fmaxf(s.w, 0.f);
    }
    acca.x += accb.x; acca.y += accb.y; acca.z += accb.z; acca.w += accb.w;
    *(float4*)(out + (long long)r * C + c4) = acca;
}

// ---------- pool1 fused with layer-1 partial reduce + bias + relu ----------

template <int C, int KSPLIT>
__global__ void k_pool_f(const int* __restrict__ rowptr, const int2* __restrict__ rec,
                         const float* __restrict__ part, const float* __restrict__ bias,
                         float* __restrict__ out, int n, int partStride) {
    constexpr int C4 = C / 4;
    int idx = blockIdx.x * blockDim.x + threadIdx.x;
    if (idx >= n * C4) return;
    int r = idx / C4, c4 = (idx - r * C4) * 4;
    int s0 = rowptr[r], s1 = rowptr[r + 1];
    float4 bb = *(const float4*)(bias + c4);
    float4 acc = make_float4(0.f, 0.f, 0.f, 0.f);
    for (int j = s0; j < s1; ++j) {
        int2 rr = rec[j];
        float v = __int_as_float(rr.y);
        float4 x = bb;
#pragma unroll
        for (int s = 0; s < KSPLIT; ++s) {
            float4 p = *(const float4*)(part + (long long)s * partStride + (long long)rr.x * C + c4);
            x.x += p.x; x.y += p.y; x.z += p.z; x.w += p.w;
        }
        acc.x += v * fmaxf(x.x, 0.f); acc.y += v * fmaxf(x.y, 0.f);
        acc.z += v * fmaxf(x.z, 0.f); acc.w += v * fmaxf(x.w, 0.f);
    }
    *(float4*)(out + (long long)r * C + c4) = acc;
}

// ---------- layer-0 direct out-GEMM (CIN=3 stride 4, COUT=32) ----------

__global__ void k_outgemm0(float* __restrict__ out, const float* __restrict__ txbase,
                           const float* __restrict__ W, const float* __restrict__ b,
                           int n) {
    int idx = blockIdx.x * blockDim.x + threadIdx.x;
    if (idx >= n * 8) return;
    int node = idx >> 3, co = (idx & 7) * 4;
    float4 acc = *(const float4*)(b + co);
#pragma unroll
    for (int k = 0; k < 6; ++k) {
        float4 xv = *(const float4*)(txbase + k * TXS + (long long)node * 4);
        const float* Wk = W + k * 96 + co;
        float4 w0 = *(const float4*)(Wk);
        float4 w1 = *(const float4*)(Wk + 32);
        float4 w2 = *(const float4*)(Wk + 64);
        acc.x += xv.x * w0.x + xv.y * w1.x + xv.z * w2.x;
        acc.y += xv.x * w0.y + xv.y * w1.y + xv.z * w2.y;
        acc.z += xv.x * w0.z + xv.y * w1.z + xv.z * w2.z;
        acc.w += xv.x * w0.w + xv.y * w1.w + xv.z * w2.w;
    }
    *(float4*)(out + (long long)node * 32 + co) = acc;
}

// ---------- node-tiled k-split out-GEMM, forced-loop (no spill) ----------
// #pragma unroll 1: live set = one chunk iteration (4 W + NT xv + acc).
// TLP (>1000 blocks) hides the load latency; no hoisting possible.

template <int CIN, int COUT, int KSPLIT, int NT>
__global__ __launch_bounds__(256, 4)
void k_outsplit4(float* __restrict__ part, const float* __restrict__ txbase,
                 const float* __restrict__ W, int n, int partStride) {
    constexpr int CO4 = COUT / 4;
    constexpr int KPER = 6 / KSPLIT;
    int per = (n / NT) * CO4;
    int idx = blockIdx.x * blockDim.x + threadIdx.x;
    if (idx >= per * KSPLIT) return;
    int s = idx / per, t = idx - s * per;
    int tile = t / CO4, co = (t - tile * CO4) * 4;
    int node0 = tile * NT;
    float4 acc[NT];
#pragma unroll
    for (int i = 0; i < NT; ++i) acc[i] = make_float4(0.f, 0.f, 0.f, 0.f);
#pragma unroll 1
    for (int kk = 0; kk < KPER; ++kk) {
        int k = s * KPER + kk;
        const float* xb = txbase + (long long)k * TXS + (long long)node0 * CIN;
        const float* Wk = W + (long long)k * CIN * COUT + co;
#pragma unroll 1
        for (int c4 = 0; c4 < CIN / 4; ++c4) {
            const float* Wr = Wk + c4 * 4 * COUT;
            float4 w0 = *(const float4*)(Wr);
            float4 w1 = *(const float4*)(Wr + COUT);
            float4 w2 = *(const float4*)(Wr + 2 * COUT);
            float4 w3 = *(const float4*)(Wr + 3 * COUT);
#pragma unroll
            for (int i = 0; i < NT; ++i) {
                float4 xv = *(const float4*)(xb + i * CIN + c4 * 4);
                acc[i].x += xv.x * w0.x + xv.y * w1.x + xv.z * w2.x + xv.w * w3.x;
                acc[i].y += xv.x * w0.y + xv.y * w1.y + xv.z * w2.y + xv.w * w3.y;
                acc[i].z += xv.x * w0.z + xv.y * w1.z + xv.z * w2.z + xv.w * w3.z;
                acc[i].w += xv.x * w0.w + xv.y * w1.w + xv.z * w2.w + xv.w * w3.w;
            }
        }
    }
    float* op = part + (long long)s * partStride + (long long)node0 * COUT + co;
#pragma unroll
    for (int i = 0; i < NT; ++i)
        *(float4*)(op + (long long)i * COUT) = acc[i];
}

// ---------- linear head, fused with layer-2 partial reduce + bias ----------

__global__ void k_linear_partial_f(const float* __restrict__ lw,
                                   const float4* __restrict__ part,
                                   const float* __restrict__ b2,
                                   float* __restrict__ partials,
                                   int len4, int len, int nblk) {
    float acc[10];
#pragma unroll
    for (int j = 0; j < 10; ++j) acc[j] = 0.f;
    const float4* b2v = (const float4*)b2;
    for (int i = blockIdx.x * blockDim.x + threadIdx.x; i < len4;
         i += gridDim.x * blockDim.x) {
        float4 xv = b2v[i & 31];
#pragma unroll
        for (int s = 0; s < 6; ++s) {
            float4 p = part[s * 200000 + i];
            xv.x += p.x; xv.y += p.y; xv.z += p.z; xv.w += p.w;
        }
#pragma unroll
        for (int j = 0; j < 10; ++j) {
            float4 wv = *(const float4*)(lw + (long long)j * len + i * 4);
            acc[j] += xv.x * wv.x + xv.y * wv.y + xv.z * wv.z + xv.w * wv.w;
        }
    }
    __shared__ float lds[4][10];
    int wid = threadIdx.x >> 6, lane = threadIdx.x & 63;
#pragma unroll
    for (int j = 0; j < 10; ++j) {
        float v = acc[j];
        for (int off = 32; off > 0; off >>= 1) v += __shfl_down(v, off, 64);
        if (lane == 0) lds[wid][j] = v;
    }
    __syncthreads();
    if (threadIdx.x < 10) {
        float s = lds[0][threadIdx.x] + lds[1][threadIdx.x] +
                  lds[2][threadIdx.x] + lds[3][threadIdx.x];
        partials[threadIdx.x * nblk + blockIdx.x] = s;
    }
}

__global__ void k_linear_final(const float* __restrict__ partials,
                               const float* __restrict__ lb,
                               float* __restrict__ out, int nblk) {
    int j = threadIdx.x >> 6, lane = threadIdx.x & 63;
    float v = 0.f;
    for (int b = lane; b < nblk; b += 64) v += partials[j * nblk + b];
    for (int off = 32; off > 0; off >>= 1) v += __shfl_down(v, off, 64);
    if (lane == 0) out[j] = lb[j] + v;
}

extern "C" void kernel_launch(void* const* d_in, const int* in_sizes, int n_in,
                              void* d_out, int out_size, void* d_ws, size_t ws_size,
                              hipStream_t stream) {
    const int cN0 = 100000, cN1 = 25000, cN2 = 6250;
    const int cE0 = 600000, cE1 = 150000, cE2 = 40000;
    const int NBLK = 512;

    const float* pos = (const float*)d_in[0];
    const int*   ei0 = (const int*)d_in[1];
    const int*   ei1 = (const int*)d_in[2];
    const int*   ei2 = (const int*)d_in[3];
    const int*   d0r = (const int*)d_in[4];
    const int*   d0c = (const int*)d_in[5];
    const float* d0v = (const float*)d_in[6];
    const int*   d1r = (const int*)d_in[7];
    const int*   d1c = (const int*)d_in[8];
    const float* d1v = (const float*)d_in[9];
    const float* W0  = (const float*)d_in[10];
    const float* b0  = (const float*)d_in[11];
    const float* W1  = (const float*)d_in[12];
    const float* b1  = (const float*)d_in[13];
    const float* W2  = (const float*)d_in[14];
    const float* b2  = (const float*)d_in[15];
    const float* lw  = (const float*)d_in[16];
    const float* lb  = (const float*)d_in[17];
    float* outZ = (float*)d_out;

    // concatenated row space: g0 g1 g2 p0 p1
    const int ntot = cN0 + cN1 + cN2 + cN1 + cN2;          // 162500
    const int Etot = cE0 + cE1 + cE2 + cN0 + cN1;          // 915000
    const int Eg   = cE0 + cE1 + cE2;                      // 790000
    const int ndinv = cN0 + cN1 + cN2;                     // 131250
    const int doff0 = 0, doff1 = cN0, doff2 = cN0 + cN1,
              doffp0 = doff2 + cN2, doffp1 = doffp0 + cN1;

    // workspace layout (4B units); int2/float4 bases 8/16B-aligned
    int*   iws    = (int*)d_ws;
    int*   gbcnt  = iws;                          // 320
    int*   gbbase = gbcnt + 320;                  // 320
    int*   rowptr = gbbase + 320;                 // 162504
    float* dinv   = (float*)(rowptr + 162504);    // 131256
    int2*  binrec = (int2*)(dinv + 131256);       // NB*BCAP int2
    int2*  rec    = binrec + (long long)NB * BCAP;// 915000 int2
    float* txbuf  = (float*)(rec + 915000);       // 6 x TXS (slot 0 = x)
    float* part   = txbuf + 6 * TXS;              // 4800000
    float* bufOut = part + 4800000;               // 3200000
    float* lpart  = bufOut + 3200000;             // 5120

    Desc5 d;
    d.rows[0] = ei0;        d.cols[0] = ei0 + cE0; d.vals[0] = nullptr;
    d.rows[1] = ei1;        d.cols[1] = ei1 + cE1; d.vals[1] = nullptr;
    d.rows[2] = ei2;        d.cols[2] = ei2 + cE2; d.vals[2] = nullptr;
    d.rows[3] = d0r;        d.cols[3] = d0c;       d.vals[3] = d0v;
    d.rows[4] = d1r;        d.cols[4] = d1c;       d.vals[4] = d1v;
    d.eoff[0] = 0;
    d.eoff[1] = cE0;
    d.eoff[2] = cE0 + cE1;
    d.eoff[3] = Eg;
    d.eoff[4] = Eg + cN0;
    d.eoff[5] = Etot;
    d.doff[0] = doff0; d.doff[1] = doff1; d.doff[2] = doff2;
    d.doff[3] = doffp0; d.doff[4] = doffp1;

    // ---- prep: pos -> tx slot 0 (stride 4) ----
    k_pad4<<<gs(cN0), TPB, 0, stream>>>(pos, (float4*)txbuf, cN0);

    // ---- binned CSR build ----
    hipMemsetAsync(gbcnt, 0, (size_t)NB * 4, stream);
    k_binA<<<(Etot + EPB - 1) / EPB, TPB, 0, stream>>>(d, gbcnt, binrec, Etot);
    k_bscan<<<1, 64, 0, stream>>>(gbcnt, gbbase);
    k_B1<<<NB, TPB, 0, stream>>>(gbcnt, gbbase, binrec, rowptr, dinv, ntot, ndinv, Etot);
    k_B2<<<NB, TPB, 0, stream>>>(gbcnt, gbbase, binrec, dinv, rec);

    // ---- Tx recurrence over contiguous slots (slot 0 = x) ----
    auto run_sprops = [&](int doffs, int n, int Cs) {
        const int* rp = rowptr + doffs;
        const float* dv = dinv + doffs;
        auto sprop = [&](int kdst, int mode) {
            const float* src = txbuf + (long long)(kdst - 1) * TXS;
            const float* prev = (kdst >= 2) ? txbuf + (long long)(kdst - 2) * TXS : nullptr;
            float* dst = txbuf + (long long)kdst * TXS;
            long long work = (long long)n * (Cs >> 2);
            if (Cs == 4)
                k_sprop_c4<<<gs(n), TPB, 0, stream>>>(rp, rec, dv, src, prev, dst, n, mode);
            else if (Cs == 32)
                k_sprop_t<32><<<gs(work), TPB, 0, stream>>>(rp, rec, dv, src, prev, dst, n, mode);
            else
                k_sprop_t<64><<<gs(work), TPB, 0, stream>>>(rp, rec, dv, src, prev, dst, n, mode);
        };
        sprop(1, 0);
        for (int k = 2; k < 6; ++k) sprop(k, 1);
    };

    // ---- layer 0: tx0 = pos4 (CIN=3 s4) -> bufOut (N0x32); pool0 -> tx slot 0 ----
    run_sprops(doff0, cN0, 4);
    k_outgemm0<<<gs((long long)cN0 * 8), TPB, 0, stream>>>(bufOut, txbuf, W0, b0, cN0);
    k_spool4_t<32><<<gs((long long)cN1 * 8), TPB, 0, stream>>>(
        rowptr + doffp0, rec, bufOut, txbuf, cN1);

    // ---- layer 1: tx (N1x32) -> part[0..2]; pool1 fused -> tx slot 0 ----
    run_sprops(doff1, cN1, 32);
    {
        const int pstride = cN1 * 64;  // 1600000
        k_outsplit4<32, 64, 3, 4><<<gs((long long)(cN1 / 4) * 16 * 3), TPB, 0, stream>>>(
            part, txbuf, W1, cN1, pstride);
        k_pool_f<64, 3><<<gs((long long)cN2 * 16), TPB, 0, stream>>>(
            rowptr + doffp1, rec, part, b1, txbuf, cN2, pstride);
    }

    // ---- layer 2: tx (N2x64) -> part[0..5]; head fused ----
    run_sprops(doff2, cN2, 64);
    {
        const int pstride = cN2 * 128;  // 800000
        k_outsplit4<64, 128, 6, 2><<<gs((long long)(cN2 / 2) * 32 * 6), TPB, 0, stream>>>(
            part, txbuf, W2, cN2, pstride);
        k_linear_partial_f<<<NBLK, TPB, 0, stream>>>(
            lw, (const float4*)part, b2, lpart, cN2 * 128 / 4, cN2 * 128, NBLK);
        k_linear_final<<<1, 640, 0, stream>>>(lpart, lb, outZ, NBLK);
    }
}